// Round 5
// baseline (5320.285 us; speedup 1.0000x reference)
//
#include <hip/hip_runtime.h>

// ---------------------------------------------------------------------------
// DeconvCG: 100 CG iterations solving (K^T K + sum w_i^2 G_i^T G_i) x = K^T y
// Persistent-kernel design: 192 blocks (3ch x 8x8 tiles of 64x64), 512 thr.
// x, r, p in registers; p-halo (P) + conv intermediate (T) in LDS.
// R5: vectorized LDS access (float4/b128; PSTR=84, TSTR=76, 16B-aligned rows);
//     F buffer removed -- P frame cells ARE the beta-recurrence state.
// Cross-block traffic: r-only 4B strips (coalesced), agent-scope relaxed
// atomics. Grid barrier fused with dot allreduce: tagged slots, parity dbuf.
// ---------------------------------------------------------------------------

static constexpr int H = 512, W = 512, CCH = 3;
static constexpr int TDIM = 64;
static constexpr int RAD = 5;
static constexpr int HALO = 10;
static constexpr int PR = TDIM + 2 * HALO;        // 84
static constexpr int PSTR = 84;                   // 336B rows: 16B-aligned
static constexpr int TR = TDIM + 2 * RAD;         // 74
static constexpr int TSTR = 76;                   // 304B rows: 16B-aligned
static constexpr int NBLK = CCH * 8 * 8;          // 192
static constexpr int NTHR = 512;
static constexpr int NITER = 100;
static constexpr int FRN = 2960;                  // frame pixels (84^2-64^2)
static constexpr int SPN = 2160;                  // strip pixels (64^2-44^2)

// ---------------- vector LDS helpers ---------------------------------------
__device__ __forceinline__ void load18(const float* __restrict__ row, float* __restrict__ v)
{
    const float4 a = *reinterpret_cast<const float4*>(row + 0);
    const float4 b = *reinterpret_cast<const float4*>(row + 4);
    const float4 c = *reinterpret_cast<const float4*>(row + 8);
    const float4 d = *reinterpret_cast<const float4*>(row + 12);
    const float2 e = *reinterpret_cast<const float2*>(row + 16);
    v[0]=a.x; v[1]=a.y; v[2]=a.z; v[3]=a.w;
    v[4]=b.x; v[5]=b.y; v[6]=b.z; v[7]=b.w;
    v[8]=c.x; v[9]=c.y; v[10]=c.z; v[11]=c.w;
    v[12]=d.x; v[13]=d.y; v[14]=d.z; v[15]=d.w;
    v[16]=e.x; v[17]=e.y;
}

// ---------------- block reduction (deterministic) --------------------------
__device__ __forceinline__ float block_reduce0(float v, float* red, int tid)
{
    __syncthreads();
    #pragma unroll
    for (int m = 32; m; m >>= 1) v += __shfl_xor(v, m, 64);
    if ((tid & 63) == 0) red[tid >> 6] = v;
    __syncthreads();
    float s = 0.f;
    if (tid == 0) {
        #pragma unroll
        for (int i = 0; i < NTHR / 64; ++i) s += red[i];
    }
    return s;          // valid on tid 0 only
}

// ---------------- fused grid-barrier + allreduce ---------------------------
__device__ __forceinline__ float allreduce_bar(unsigned long long* slots, unsigned seq,
                                               float thread_partial,
                                               float* red, float* bc, int tid, int bid)
{
    float part = block_reduce0(thread_partial, red, tid);
    asm volatile("s_waitcnt vmcnt(0)" ::: "memory");   // drain my strip stores/loads
    __syncthreads();
    unsigned long long* buf = slots + (size_t)(seq & 1u) * 256;
    if (tid == 0) {
        unsigned long long u = ((unsigned long long)seq << 32)
                             | (unsigned long long)__float_as_uint(part);
        __hip_atomic_store(&buf[bid], u, __ATOMIC_RELAXED, __HIP_MEMORY_SCOPE_AGENT);
    }
    float mine = 0.f;
    if (tid < NBLK) {
        unsigned long long v;
        for (;;) {
            v = __hip_atomic_load(&buf[tid], __ATOMIC_RELAXED, __HIP_MEMORY_SCOPE_AGENT);
            if ((unsigned)(v >> 32) == seq) break;
            __builtin_amdgcn_s_sleep(1);
        }
        mine = __uint_as_float((unsigned)v);
    }
    float s = block_reduce0(mine, red, tid);
    if (tid == 0) *bc = s;
    __syncthreads();
    return *bc;        // bitwise-identical in every block
}

// ---------------- 11x11 convs ----------------------------------------------
__device__ __forceinline__ void conv_fwd_phase(const float* __restrict__ kern,
                                               const float* __restrict__ P_,
                                               float* __restrict__ T_,
                                               int by0, int bx0, int tid)
{
    for (int seg = tid; seg < TR * 10; seg += NTHR) {
        int ry  = seg / 10;
        int rx0 = (seg - ry * 10) << 3;
        int gy  = by0 - RAD + ry;
        bool rowIn = (gy >= 0 && gy < H);
        float acc[8];
        #pragma unroll
        for (int j = 0; j < 8; ++j) acc[j] = 0.f;
        for (int a = 0; a < 11; ++a) {
            float v[18];
            load18(P_ + (ry + a) * PSTR + rx0, v);
            #pragma unroll
            for (int b = 0; b < 11; ++b) {
                float kw = kern[a * 11 + b];
                #pragma unroll
                for (int j = 0; j < 8; ++j) acc[j] = fmaf(v[b + j], kw, acc[j]);
            }
        }
        #pragma unroll
        for (int j = 0; j < 8; ++j) {
            int gx = bx0 - RAD + rx0 + j;
            bool in = rowIn && gx >= 0 && gx < W;
            acc[j] = in ? acc[j] : 0.f;          // zero outside image
        }
        float* dst = T_ + ry * TSTR + rx0;
        if (rx0 < 72) {
            *reinterpret_cast<float4*>(dst)     = make_float4(acc[0], acc[1], acc[2], acc[3]);
            *reinterpret_cast<float4*>(dst + 4) = make_float4(acc[4], acc[5], acc[6], acc[7]);
        } else {                                  // rx0==72: only cols 72,73 valid
            dst[0] = acc[0];
            dst[1] = acc[1];
        }
    }
}

// vector flip conv: requires col0 32B-aligned (multiple of 8 floats)
__device__ __forceinline__ void conv11_flip_acc_v(const float* __restrict__ src, int stride,
                                                  int row0, int col0,
                                                  const float* __restrict__ kern,
                                                  float acc[8])
{
    for (int a = 0; a < 11; ++a) {
        float v[18];
        load18(src + (row0 + a) * stride + col0, v);
        #pragma unroll
        for (int b = 0; b < 11; ++b) {
            float kw = kern[(10 - a) * 11 + (10 - b)];
            #pragma unroll
            for (int j = 0; j < 8; ++j) acc[j] = fmaf(v[b + j], kw, acc[j]);
        }
    }
}

// scalar flip conv (init only: misaligned col0)
__device__ __forceinline__ void conv11_flip_acc_s(const float* __restrict__ src, int stride,
                                                  int row0, int col0,
                                                  const float* __restrict__ kern,
                                                  float acc[8])
{
    for (int a = 0; a < 11; ++a) {
        const float* row = src + (row0 + a) * stride + col0;
        float v[18];
        #pragma unroll
        for (int b = 0; b < 18; ++b) v[b] = row[b];
        #pragma unroll
        for (int b = 0; b < 11; ++b) {
            float kw = kern[(10 - a) * 11 + (10 - b)];
            #pragma unroll
            for (int j = 0; j < 8; ++j) acc[j] = fmaf(v[b + j], kw, acc[j]);
        }
    }
}

// ---------------- regularizer term -----------------------------------------
__device__ __forceinline__ void reg_acc(const float* __restrict__ P_,
                                        const float* __restrict__ CB_,
                                        const float* __restrict__ gk,
                                        float w0sq, float w1sq,
                                        int oy, int ox0, int gy, int gx0,
                                        float acc[8])
{
    bool interior = (gy >= 1 && gy < H - 1 && gx0 >= 1 && gx0 <= W - 9);
    if (interior) {
        for (int a = 0; a < 5; ++a) {
            const float* row = P_ + (oy + 8 + a) * PSTR + ox0 + 8;   // 32B-aligned
            const float4 q0 = *reinterpret_cast<const float4*>(row);
            const float4 q1 = *reinterpret_cast<const float4*>(row + 4);
            const float4 q2 = *reinterpret_cast<const float4*>(row + 8);
            float v[12] = {q0.x,q0.y,q0.z,q0.w, q1.x,q1.y,q1.z,q1.w, q2.x,q2.y,q2.z,q2.w};
            #pragma unroll
            for (int b = 0; b < 5; ++b) {
                float cb = CB_[a * 5 + b];
                #pragma unroll
                for (int j = 0; j < 8; ++j) acc[j] = fmaf(v[b + j], cb, acc[j]);
            }
        }
    } else {
        for (int j = 0; j < 8; ++j) {
            int gx = gx0 + j;
            float racc = 0.f;
            for (int dy = -1; dy <= 1; ++dy)
                for (int dx = -1; dx <= 1; ++dx) {
                    int qy = gy + dy, qx = gx + dx;
                    if (qy >= 0 && qy < H && qx >= 0 && qx < W) {
                        float u0 = 0.f, u1 = 0.f;
                        int pr0 = oy + 10 + dy - 1, pc0 = ox0 + j + 10 + dx - 1;
                        for (int sy = 0; sy < 3; ++sy)
                            for (int sx = 0; sx < 3; ++sx) {
                                float pv = P_[(pr0 + sy) * PSTR + pc0 + sx];
                                u0 = fmaf(pv, gk[sy * 3 + sx], u0);
                                u1 = fmaf(pv, gk[9 + sy * 3 + sx], u1);
                            }
                        racc += w0sq * gk[(1 - dy) * 3 + (1 - dx)] * u0
                              + w1sq * gk[9 + (1 - dy) * 3 + (1 - dx)] * u1;
                    }
                }
            acc[j] += racc;
        }
    }
}

// ---------------- slot init (fresh tags each call) -------------------------
__global__ void slot_init(unsigned long long* slots) { slots[threadIdx.x] = 0ull; }

// ---------------- main persistent kernel -----------------------------------
__global__ void __launch_bounds__(NTHR)
deconv_cg(const float* __restrict__ img, const float* __restrict__ kern,
          const float* __restrict__ wts, const float* __restrict__ gk,
          float* __restrict__ out, float* __restrict__ ws)
{
    __shared__ alignas(16) float P[PR * PSTR + 8];   // p halo region (persistent)
    __shared__ alignas(16) float T[TR * TSTR + 8];   // conv intermediate / r staging
    __shared__ float CB[25];
    __shared__ float red[NTHR / 64];
    __shared__ float bc;

    const int tid = threadIdx.x;
    const int bid = blockIdx.x;
    const int ch  = bid / 64;
    const int tt  = bid - ch * 64;
    const int by0 = (tt >> 3) * TDIM;
    const int bx0 = (tt & 7) * TDIM;

    const float* imgc = img + ch * H * W;
    unsigned long long* slots = (unsigned long long*)ws;   // [2][256] u64
    float* Hc = ws + 1024 + (size_t)ch * H * W;            // published r

    const float w0 = wts[0], w1 = wts[1];
    const float w0sq = w0 * w0, w1sq = w1 * w1;

    if (tid < 25) {
        int ty = tid / 5 - 2, tx = tid % 5 - 2;
        float s = 0.f;
        for (int ay = 0; ay < 3; ++ay)
            for (int ax = 0; ax < 3; ++ax) {
                int by_ = ay + ty, bx_ = ax + tx;
                if (by_ >= 0 && by_ < 3 && bx_ >= 0 && bx_ < 3)
                    s += w0sq * gk[ay * 3 + ax] * gk[by_ * 3 + bx_]
                       + w1sq * gk[9 + ay * 3 + ax] * gk[9 + by_ * 3 + bx_];
            }
        CB[tid] = s;
    }

    // owned-pixel mapping: thread -> 8 consecutive-x pixels of one row
    const int oy  = tid >> 3;
    const int ox0 = (tid & 7) << 3;
    const int gy  = by0 + oy;
    const int gx0 = bx0 + ox0;

    // ---- precomputed frame map (iteration-invariant): 6 slots/thread ------
    // frame = P [84x84] minus owned [10,74)^2: rows 0..9 (840), rows 74..83
    // (840), rows 10..73 x cols {0..9, 74..83} (1280)
    int fP[6], fG[6];
    #pragma unroll
    for (int k = 0; k < 6; ++k) {
        int idx = tid + k * NTHR;
        fP[k] = -1; fG[k] = -1;
        if (idx < FRN) {
            int py, px;
            if (idx < 840)       { py = idx / 84;              px = idx - py * 84; }
            else if (idx < 1680) { int t = idx - 840;  py = 74 + t / 84; px = t - (t / 84) * 84; }
            else                 { int t = idx - 1680; py = 10 + t / 20;
                                   int c = t - (t / 20) * 20;  px = (c < 10) ? c : (c + 64); }
            int iy = by0 - HALO + py, ix = bx0 - HALO + px;
            if (iy >= 0 && iy < H && ix >= 0 && ix < W) {
                fP[k] = py * PSTR + px;
                fG[k] = iy * W + ix;
            }
        }
    }
    // ---- precomputed strip publish map: 5 slots/thread ---------------------
    int pT[5], pG[5];
    #pragma unroll
    for (int k = 0; k < 5; ++k) {
        int idx = tid + k * NTHR;
        pT[k] = -1; pG[k] = 0;
        if (idx < SPN) {
            int sy, sx;
            if (idx < 640)       { sy = idx >> 6;              sx = idx & 63; }
            else if (idx < 1280) { int t = idx - 640;  sy = 54 + (t >> 6); sx = t & 63; }
            else                 { int t = idx - 1280; sy = 10 + t / 20;
                                   int c = t - (t / 20) * 20;  sx = (c < 10) ? c : (c + 44); }
            pT[k] = sy * TSTR + sx;
            pG[k] = (by0 + sy) * W + bx0 + sx;
        }
    }

    float xr[8], rr[8], pr[8];

    // ================= init: r0 = K^T y - A*x0, x0 = image, p0 = r0 ========
    for (int idx = tid; idx < PR * PR; idx += NTHR) {
        int py = idx / PR, px = idx - py * PR;
        int iy = by0 - HALO + py, ix = bx0 - HALO + px;
        float v = 0.f;
        if (iy >= 0 && iy < H && ix >= 0 && ix < W) v = imgc[iy * W + ix];
        P[py * PSTR + px] = v;
    }
    __syncthreads();
    conv_fwd_phase(kern, P, T, by0, bx0, tid);
    __syncthreads();
    float rTr, beta = 0.f;
    {
        float accA[8], accB[8];
        #pragma unroll
        for (int j = 0; j < 8; ++j) { accA[j] = 0.f; accB[j] = 0.f; }
        conv11_flip_acc_v(T, TSTR, oy, ox0, kern, accA);          // K^T K x0
        conv11_flip_acc_s(P, PSTR, oy + 5, ox0 + 5, kern, accB);  // b = K^T y
        reg_acc(P, CB, gk, w0sq, w1sq, oy, ox0, gy, gx0, accA);   // + reg x0
        float dr = 0.f;
        #pragma unroll
        for (int j = 0; j < 8; ++j) {
            float r0 = accB[j] - accA[j];
            rr[j] = r0;  pr[j] = r0;
            xr[j] = P[(oy + HALO) * PSTR + ox0 + HALO + j];
            dr = fmaf(r0, r0, dr);
        }
        __syncthreads();                         // everyone done reading T
        float* st = T + oy * TSTR + ox0;
        *reinterpret_cast<float4*>(st)     = make_float4(rr[0], rr[1], rr[2], rr[3]);
        *reinterpret_cast<float4*>(st + 4) = make_float4(rr[4], rr[5], rr[6], rr[7]);
        __syncthreads();
        #pragma unroll
        for (int k = 0; k < 5; ++k)
            if (pT[k] >= 0)
                __hip_atomic_store(&Hc[pG[k]], T[pT[k]],
                                   __ATOMIC_RELAXED, __HIP_MEMORY_SCOPE_AGENT);
        rTr = allreduce_bar(slots, 1u, dr, red, &bc, tid, bid);
    }

    // ================= CG main loop ========================================
    for (int it = 0; it < NITER; ++it) {
        // phase 1: p = r + beta*p. Owned cells from regs; frame cells updated
        // in place: P[f] = fmaf(beta, P[f]_old, r_neighbor) == neighbor's pr.
        #pragma unroll
        for (int j = 0; j < 8; ++j) pr[j] = fmaf(beta, pr[j], rr[j]);
        float fv[6];
        #pragma unroll
        for (int k = 0; k < 6; ++k)
            fv[k] = (fG[k] >= 0)
                  ? __hip_atomic_load(&Hc[fG[k]], __ATOMIC_RELAXED, __HIP_MEMORY_SCOPE_AGENT)
                  : 0.f;
        #pragma unroll
        for (int k = 0; k < 6; ++k)
            if (fG[k] >= 0)
                P[fP[k]] = fmaf(beta, P[fP[k]], fv[k]);
        {
            float* ow = P + (oy + HALO) * PSTR + ox0 + HALO;   // 8B-aligned
            *reinterpret_cast<float2*>(ow)     = make_float2(pr[0], pr[1]);
            *reinterpret_cast<float2*>(ow + 2) = make_float2(pr[2], pr[3]);
            *reinterpret_cast<float2*>(ow + 4) = make_float2(pr[4], pr[5]);
            *reinterpret_cast<float2*>(ow + 6) = make_float2(pr[6], pr[7]);
        }
        __syncthreads();

        // phase 2: t = conv(p, k)
        conv_fwd_phase(kern, P, T, by0, bx0, tid);
        __syncthreads();

        // phase 3: Ap on owned tile, dot(p,Ap)
        float Ap[8];
        float dp = 0.f;
        {
            float acc[8];
            #pragma unroll
            for (int j = 0; j < 8; ++j) acc[j] = 0.f;
            conv11_flip_acc_v(T, TSTR, oy, ox0, kern, acc);
            reg_acc(P, CB, gk, w0sq, w1sq, oy, ox0, gy, gx0, acc);
            #pragma unroll
            for (int j = 0; j < 8; ++j) {
                Ap[j] = acc[j];
                dp = fmaf(pr[j], Ap[j], dp);
            }
        }
        float pAp   = allreduce_bar(slots, 2u * it + 2u, dp, red, &bc, tid, bid);
        float alpha = rTr / pAp;

        // phase 4: update x, r; stage r in T; coalesced strip publish
        float dr = 0.f;
        #pragma unroll
        for (int j = 0; j < 8; ++j) {
            xr[j] = fmaf(alpha, pr[j], xr[j]);
            rr[j] = fmaf(-alpha, Ap[j], rr[j]);
            dr = fmaf(rr[j], rr[j], dr);
        }
        {
            float* st = T + oy * TSTR + ox0;
            *reinterpret_cast<float4*>(st)     = make_float4(rr[0], rr[1], rr[2], rr[3]);
            *reinterpret_cast<float4*>(st + 4) = make_float4(rr[4], rr[5], rr[6], rr[7]);
        }
        __syncthreads();
        #pragma unroll
        for (int k = 0; k < 5; ++k)
            if (pT[k] >= 0)
                __hip_atomic_store(&Hc[pG[k]], T[pT[k]],
                                   __ATOMIC_RELAXED, __HIP_MEMORY_SCOPE_AGENT);
        float s = allreduce_bar(slots, 2u * it + 3u, dr, red, &bc, tid, bid);
        beta = s / rTr;
        rTr  = s;
    }

    // write x
    float* outc = out + ch * H * W;
    #pragma unroll
    for (int j = 0; j < 8; ++j) outc[gy * W + gx0 + j] = xr[j];
}

// ---------------------------------------------------------------------------
extern "C" void kernel_launch(void* const* d_in, const int* in_sizes, int n_in,
                              void* d_out, int out_size, void* d_ws, size_t ws_size,
                              hipStream_t stream)
{
    (void)in_sizes; (void)n_in; (void)out_size; (void)ws_size;
    const float* img  = (const float*)d_in[0];   // [3,512,512]
    const float* kern = (const float*)d_in[1];   // [11,11]
    const float* wts  = (const float*)d_in[2];   // [2]
    const float* gk   = (const float*)d_in[3];   // [2,3,3]
    float* out = (float*)d_out;
    float* ws  = (float*)d_ws;

    slot_init<<<1, 512, 0, stream>>>((unsigned long long*)ws);
    deconv_cg<<<dim3(NBLK), dim3(NTHR), 0, stream>>>(img, kern, wts, gk, out, ws);
}

// Round 6
// 4710.821 us; speedup vs baseline: 1.1294x; 1.1294x over previous
//
#include <hip/hip_runtime.h>

// ---------------------------------------------------------------------------
// DeconvCG: 100 CG iterations solving (K^T K + sum w_i^2 G_i^T G_i) x = K^T y
// Persistent-kernel design: 192 blocks (3ch x 8x8 tiles of 64x64), 512 thr.
// R6: (a) VGPR clamped to 256 (asm clobber v255) -> 8 waves/CU -> EXACTLY one
//     block per CU; the dispatcher can never pack 2-3 blocks on one CU (the
//     R2/R5 regression: packing desynchronized blocks -> 4x barrier-poll HBM
//     traffic + 36ms outliers).
//     (b) row-per-lane conv mapping: consecutive lanes read consecutive LDS
//     ROWS (stride 84/76 floats -> 8-cycle bank offsets, <=2-way conflicts)
//     instead of consecutive col-chunks (3-way on bank quads 0/8/16/24).
// x, r, p in registers; p-halo (P) + conv intermediate (T) in LDS (vector
// b128 access). Cross-block traffic: r-only 4B strips, agent-scope relaxed
// atomics. Grid barrier fused with dot allreduce: tagged slots, parity dbuf.
// ---------------------------------------------------------------------------

static constexpr int H = 512, W = 512, CCH = 3;
static constexpr int TDIM = 64;
static constexpr int RAD = 5;
static constexpr int HALO = 10;
static constexpr int PR = TDIM + 2 * HALO;        // 84
static constexpr int PSTR = 84;                   // 336B rows: 16B-aligned
static constexpr int TR = TDIM + 2 * RAD;         // 74
static constexpr int TSTR = 76;                   // 304B rows: 16B-aligned
static constexpr int NBLK = CCH * 8 * 8;          // 192
static constexpr int NTHR = 512;
static constexpr int NITER = 100;
static constexpr int FRN = 2960;                  // frame pixels (84^2-64^2)
static constexpr int SPN = 2160;                  // strip pixels (64^2-44^2)

// ---------------- vector LDS helpers ---------------------------------------
__device__ __forceinline__ void load18(const float* __restrict__ row, float* __restrict__ v)
{
    const float4 a = *reinterpret_cast<const float4*>(row + 0);
    const float4 b = *reinterpret_cast<const float4*>(row + 4);
    const float4 c = *reinterpret_cast<const float4*>(row + 8);
    const float4 d = *reinterpret_cast<const float4*>(row + 12);
    const float2 e = *reinterpret_cast<const float2*>(row + 16);
    v[0]=a.x; v[1]=a.y; v[2]=a.z; v[3]=a.w;
    v[4]=b.x; v[5]=b.y; v[6]=b.z; v[7]=b.w;
    v[8]=c.x; v[9]=c.y; v[10]=c.z; v[11]=c.w;
    v[12]=d.x; v[13]=d.y; v[14]=d.z; v[15]=d.w;
    v[16]=e.x; v[17]=e.y;
}

// ---------------- block reduction (deterministic) --------------------------
__device__ __forceinline__ float block_reduce0(float v, float* red, int tid)
{
    __syncthreads();
    #pragma unroll
    for (int m = 32; m; m >>= 1) v += __shfl_xor(v, m, 64);
    if ((tid & 63) == 0) red[tid >> 6] = v;
    __syncthreads();
    float s = 0.f;
    if (tid == 0) {
        #pragma unroll
        for (int i = 0; i < NTHR / 64; ++i) s += red[i];
    }
    return s;          // valid on tid 0 only
}

// ---------------- fused grid-barrier + allreduce ---------------------------
__device__ __forceinline__ float allreduce_bar(unsigned long long* slots, unsigned seq,
                                               float thread_partial,
                                               float* red, float* bc, int tid, int bid)
{
    float part = block_reduce0(thread_partial, red, tid);
    asm volatile("s_waitcnt vmcnt(0)" ::: "memory");   // drain my strip stores/loads
    __syncthreads();
    unsigned long long* buf = slots + (size_t)(seq & 1u) * 256;
    if (tid == 0) {
        unsigned long long u = ((unsigned long long)seq << 32)
                             | (unsigned long long)__float_as_uint(part);
        __hip_atomic_store(&buf[bid], u, __ATOMIC_RELAXED, __HIP_MEMORY_SCOPE_AGENT);
    }
    float mine = 0.f;
    if (tid < NBLK) {
        unsigned long long v;
        for (;;) {
            v = __hip_atomic_load(&buf[tid], __ATOMIC_RELAXED, __HIP_MEMORY_SCOPE_AGENT);
            if ((unsigned)(v >> 32) == seq) break;
            __builtin_amdgcn_s_sleep(1);
        }
        mine = __uint_as_float((unsigned)v);
    }
    float s = block_reduce0(mine, red, tid);
    if (tid == 0) *bc = s;
    __syncthreads();
    return *bc;        // bitwise-identical in every block
}

// ---------------- 11x11 convs ----------------------------------------------
// row-per-lane seg decomposition: seg = chunk*74 + ry, consecutive lanes ->
// consecutive rows -> LDS bank offsets cycle over 8 values -> <=2-way.
__device__ __forceinline__ void conv_fwd_phase(const float* __restrict__ kern,
                                               const float* __restrict__ P_,
                                               float* __restrict__ T_,
                                               int by0, int bx0, int tid)
{
    for (int seg = tid; seg < TR * 10; seg += NTHR) {
        int chunk = seg / TR;                 // 0..9
        int ry    = seg - chunk * TR;         // 0..73
        int rx0   = chunk << 3;
        int gy    = by0 - RAD + ry;
        bool rowIn = (gy >= 0 && gy < H);
        float acc[8];
        #pragma unroll
        for (int j = 0; j < 8; ++j) acc[j] = 0.f;
        for (int a = 0; a < 11; ++a) {
            float v[18];
            load18(P_ + (ry + a) * PSTR + rx0, v);
            #pragma unroll
            for (int b = 0; b < 11; ++b) {
                float kw = kern[a * 11 + b];
                #pragma unroll
                for (int j = 0; j < 8; ++j) acc[j] = fmaf(v[b + j], kw, acc[j]);
            }
        }
        #pragma unroll
        for (int j = 0; j < 8; ++j) {
            int gx = bx0 - RAD + rx0 + j;
            bool in = rowIn && gx >= 0 && gx < W;
            acc[j] = in ? acc[j] : 0.f;          // zero outside image
        }
        float* dst = T_ + ry * TSTR + rx0;
        if (rx0 < 72) {
            *reinterpret_cast<float4*>(dst)     = make_float4(acc[0], acc[1], acc[2], acc[3]);
            *reinterpret_cast<float4*>(dst + 4) = make_float4(acc[4], acc[5], acc[6], acc[7]);
        } else {                                  // rx0==72: only cols 72,73 valid
            dst[0] = acc[0];
            dst[1] = acc[1];
        }
    }
}

// vector flip conv: requires col0 32B-aligned (multiple of 8 floats)
__device__ __forceinline__ void conv11_flip_acc_v(const float* __restrict__ src, int stride,
                                                  int row0, int col0,
                                                  const float* __restrict__ kern,
                                                  float acc[8])
{
    for (int a = 0; a < 11; ++a) {
        float v[18];
        load18(src + (row0 + a) * stride + col0, v);
        #pragma unroll
        for (int b = 0; b < 11; ++b) {
            float kw = kern[(10 - a) * 11 + (10 - b)];
            #pragma unroll
            for (int j = 0; j < 8; ++j) acc[j] = fmaf(v[b + j], kw, acc[j]);
        }
    }
}

// scalar flip conv (init only: misaligned col0)
__device__ __forceinline__ void conv11_flip_acc_s(const float* __restrict__ src, int stride,
                                                  int row0, int col0,
                                                  const float* __restrict__ kern,
                                                  float acc[8])
{
    for (int a = 0; a < 11; ++a) {
        const float* row = src + (row0 + a) * stride + col0;
        float v[18];
        #pragma unroll
        for (int b = 0; b < 18; ++b) v[b] = row[b];
        #pragma unroll
        for (int b = 0; b < 11; ++b) {
            float kw = kern[(10 - a) * 11 + (10 - b)];
            #pragma unroll
            for (int j = 0; j < 8; ++j) acc[j] = fmaf(v[b + j], kw, acc[j]);
        }
    }
}

// ---------------- regularizer term -----------------------------------------
__device__ __forceinline__ void reg_acc(const float* __restrict__ P_,
                                        const float* __restrict__ CB_,
                                        const float* __restrict__ gk,
                                        float w0sq, float w1sq,
                                        int oy, int ox0, int gy, int gx0,
                                        float acc[8])
{
    bool interior = (gy >= 1 && gy < H - 1 && gx0 >= 1 && gx0 <= W - 9);
    if (interior) {
        for (int a = 0; a < 5; ++a) {
            const float* row = P_ + (oy + 8 + a) * PSTR + ox0 + 8;   // 32B-aligned
            const float4 q0 = *reinterpret_cast<const float4*>(row);
            const float4 q1 = *reinterpret_cast<const float4*>(row + 4);
            const float4 q2 = *reinterpret_cast<const float4*>(row + 8);
            float v[12] = {q0.x,q0.y,q0.z,q0.w, q1.x,q1.y,q1.z,q1.w, q2.x,q2.y,q2.z,q2.w};
            #pragma unroll
            for (int b = 0; b < 5; ++b) {
                float cb = CB_[a * 5 + b];
                #pragma unroll
                for (int j = 0; j < 8; ++j) acc[j] = fmaf(v[b + j], cb, acc[j]);
            }
        }
    } else {
        for (int j = 0; j < 8; ++j) {
            int gx = gx0 + j;
            float racc = 0.f;
            for (int dy = -1; dy <= 1; ++dy)
                for (int dx = -1; dx <= 1; ++dx) {
                    int qy = gy + dy, qx = gx + dx;
                    if (qy >= 0 && qy < H && qx >= 0 && qx < W) {
                        float u0 = 0.f, u1 = 0.f;
                        int pr0 = oy + 10 + dy - 1, pc0 = ox0 + j + 10 + dx - 1;
                        for (int sy = 0; sy < 3; ++sy)
                            for (int sx = 0; sx < 3; ++sx) {
                                float pv = P_[(pr0 + sy) * PSTR + pc0 + sx];
                                u0 = fmaf(pv, gk[sy * 3 + sx], u0);
                                u1 = fmaf(pv, gk[9 + sy * 3 + sx], u1);
                            }
                        racc += w0sq * gk[(1 - dy) * 3 + (1 - dx)] * u0
                              + w1sq * gk[9 + (1 - dy) * 3 + (1 - dx)] * u1;
                    }
                }
            acc[j] += racc;
        }
    }
}

// ---------------- slot init (fresh tags each call) -------------------------
__global__ void slot_init(unsigned long long* slots) { slots[threadIdx.x] = 0ull; }

// ---------------- main persistent kernel -----------------------------------
__global__ void __launch_bounds__(NTHR)
__attribute__((amdgpu_waves_per_eu(2, 2)))
deconv_cg(const float* __restrict__ img, const float* __restrict__ kern,
          const float* __restrict__ wts, const float* __restrict__ gk,
          float* __restrict__ out, float* __restrict__ ws)
{
    // Force VGPR_Count = 256: caps occupancy at 8 waves/CU -> exactly one
    // 512-thread block per CU. Packing 2+ grid-barrier blocks on a CU halves
    // their speed and stalls the whole grid at every barrier (R2/R5).
    asm volatile("" ::: "v255");

    __shared__ alignas(16) float P[PR * PSTR + 8];   // p halo region (persistent)
    __shared__ alignas(16) float T[TR * TSTR + 8];   // conv intermediate / r staging
    __shared__ float CB[25];
    __shared__ float red[NTHR / 64];
    __shared__ float bc;

    const int tid = threadIdx.x;
    const int bid = blockIdx.x;
    const int ch  = bid / 64;
    const int tt  = bid - ch * 64;
    const int by0 = (tt >> 3) * TDIM;
    const int bx0 = (tt & 7) * TDIM;

    const float* imgc = img + ch * H * W;
    unsigned long long* slots = (unsigned long long*)ws;   // [2][256] u64
    float* Hc = ws + 1024 + (size_t)ch * H * W;            // published r

    const float w0 = wts[0], w1 = wts[1];
    const float w0sq = w0 * w0, w1sq = w1 * w1;

    if (tid < 25) {
        int ty = tid / 5 - 2, tx = tid % 5 - 2;
        float s = 0.f;
        for (int ay = 0; ay < 3; ++ay)
            for (int ax = 0; ax < 3; ++ax) {
                int by_ = ay + ty, bx_ = ax + tx;
                if (by_ >= 0 && by_ < 3 && bx_ >= 0 && bx_ < 3)
                    s += w0sq * gk[ay * 3 + ax] * gk[by_ * 3 + bx_]
                       + w1sq * gk[9 + ay * 3 + ax] * gk[9 + by_ * 3 + bx_];
            }
        CB[tid] = s;
    }

    // owned-pixel mapping, ROW-PER-LANE: lane = row, wave = col-chunk.
    // All 64 lanes of a wave read different LDS rows -> <=2-way conflicts.
    const int oy  = tid & 63;
    const int ox0 = (tid >> 6) << 3;
    const int gy  = by0 + oy;
    const int gx0 = bx0 + ox0;

    // ---- precomputed frame map (iteration-invariant): 6 slots/thread ------
    // frame = P [84x84] minus owned [10,74)^2: rows 0..9 (840), rows 74..83
    // (840), rows 10..73 x cols {0..9, 74..83} (1280)
    int fP[6], fG[6];
    #pragma unroll
    for (int k = 0; k < 6; ++k) {
        int idx = tid + k * NTHR;
        fP[k] = -1; fG[k] = -1;
        if (idx < FRN) {
            int py, px;
            if (idx < 840)       { py = idx / 84;              px = idx - py * 84; }
            else if (idx < 1680) { int t = idx - 840;  py = 74 + t / 84; px = t - (t / 84) * 84; }
            else                 { int t = idx - 1680; py = 10 + t / 20;
                                   int c = t - (t / 20) * 20;  px = (c < 10) ? c : (c + 64); }
            int iy = by0 - HALO + py, ix = bx0 - HALO + px;
            if (iy >= 0 && iy < H && ix >= 0 && ix < W) {
                fP[k] = py * PSTR + px;
                fG[k] = iy * W + ix;
            }
        }
    }
    // ---- precomputed strip publish map: 5 slots/thread ---------------------
    int pT[5], pG[5];
    #pragma unroll
    for (int k = 0; k < 5; ++k) {
        int idx = tid + k * NTHR;
        pT[k] = -1; pG[k] = 0;
        if (idx < SPN) {
            int sy, sx;
            if (idx < 640)       { sy = idx >> 6;              sx = idx & 63; }
            else if (idx < 1280) { int t = idx - 640;  sy = 54 + (t >> 6); sx = t & 63; }
            else                 { int t = idx - 1280; sy = 10 + t / 20;
                                   int c = t - (t / 20) * 20;  sx = (c < 10) ? c : (c + 44); }
            pT[k] = sy * TSTR + sx;
            pG[k] = (by0 + sy) * W + bx0 + sx;
        }
    }

    float xr[8], rr[8], pr[8];

    // ================= init: r0 = K^T y - A*x0, x0 = image, p0 = r0 ========
    for (int idx = tid; idx < PR * PR; idx += NTHR) {
        int py = idx / PR, px = idx - py * PR;
        int iy = by0 - HALO + py, ix = bx0 - HALO + px;
        float v = 0.f;
        if (iy >= 0 && iy < H && ix >= 0 && ix < W) v = imgc[iy * W + ix];
        P[py * PSTR + px] = v;
    }
    __syncthreads();
    conv_fwd_phase(kern, P, T, by0, bx0, tid);
    __syncthreads();
    float rTr, beta = 0.f;
    {
        float accA[8], accB[8];
        #pragma unroll
        for (int j = 0; j < 8; ++j) { accA[j] = 0.f; accB[j] = 0.f; }
        conv11_flip_acc_v(T, TSTR, oy, ox0, kern, accA);          // K^T K x0
        conv11_flip_acc_s(P, PSTR, oy + 5, ox0 + 5, kern, accB);  // b = K^T y
        reg_acc(P, CB, gk, w0sq, w1sq, oy, ox0, gy, gx0, accA);   // + reg x0
        float dr = 0.f;
        #pragma unroll
        for (int j = 0; j < 8; ++j) {
            float r0 = accB[j] - accA[j];
            rr[j] = r0;  pr[j] = r0;
            xr[j] = P[(oy + HALO) * PSTR + ox0 + HALO + j];
            dr = fmaf(r0, r0, dr);
        }
        __syncthreads();                         // everyone done reading T
        float* st = T + oy * TSTR + ox0;
        *reinterpret_cast<float4*>(st)     = make_float4(rr[0], rr[1], rr[2], rr[3]);
        *reinterpret_cast<float4*>(st + 4) = make_float4(rr[4], rr[5], rr[6], rr[7]);
        __syncthreads();
        #pragma unroll
        for (int k = 0; k < 5; ++k)
            if (pT[k] >= 0)
                __hip_atomic_store(&Hc[pG[k]], T[pT[k]],
                                   __ATOMIC_RELAXED, __HIP_MEMORY_SCOPE_AGENT);
        rTr = allreduce_bar(slots, 1u, dr, red, &bc, tid, bid);
    }

    // ================= CG main loop ========================================
    for (int it = 0; it < NITER; ++it) {
        // phase 1: p = r + beta*p. Owned cells from regs; frame cells updated
        // in place: P[f] = fmaf(beta, P[f]_old, r_neighbor) == neighbor's pr.
        #pragma unroll
        for (int j = 0; j < 8; ++j) pr[j] = fmaf(beta, pr[j], rr[j]);
        float fv[6];
        #pragma unroll
        for (int k = 0; k < 6; ++k)
            fv[k] = (fG[k] >= 0)
                  ? __hip_atomic_load(&Hc[fG[k]], __ATOMIC_RELAXED, __HIP_MEMORY_SCOPE_AGENT)
                  : 0.f;
        #pragma unroll
        for (int k = 0; k < 6; ++k)
            if (fG[k] >= 0)
                P[fP[k]] = fmaf(beta, P[fP[k]], fv[k]);
        {
            float* ow = P + (oy + HALO) * PSTR + ox0 + HALO;   // 8B-aligned
            *reinterpret_cast<float2*>(ow)     = make_float2(pr[0], pr[1]);
            *reinterpret_cast<float2*>(ow + 2) = make_float2(pr[2], pr[3]);
            *reinterpret_cast<float2*>(ow + 4) = make_float2(pr[4], pr[5]);
            *reinterpret_cast<float2*>(ow + 6) = make_float2(pr[6], pr[7]);
        }
        __syncthreads();

        // phase 2: t = conv(p, k)
        conv_fwd_phase(kern, P, T, by0, bx0, tid);
        __syncthreads();

        // phase 3: Ap on owned tile, dot(p,Ap)
        float Ap[8];
        float dp = 0.f;
        {
            float acc[8];
            #pragma unroll
            for (int j = 0; j < 8; ++j) acc[j] = 0.f;
            conv11_flip_acc_v(T, TSTR, oy, ox0, kern, acc);
            reg_acc(P, CB, gk, w0sq, w1sq, oy, ox0, gy, gx0, acc);
            #pragma unroll
            for (int j = 0; j < 8; ++j) {
                Ap[j] = acc[j];
                dp = fmaf(pr[j], Ap[j], dp);
            }
        }
        float pAp   = allreduce_bar(slots, 2u * it + 2u, dp, red, &bc, tid, bid);
        float alpha = rTr / pAp;

        // phase 4: update x, r; stage r in T; coalesced strip publish
        float dr = 0.f;
        #pragma unroll
        for (int j = 0; j < 8; ++j) {
            xr[j] = fmaf(alpha, pr[j], xr[j]);
            rr[j] = fmaf(-alpha, Ap[j], rr[j]);
            dr = fmaf(rr[j], rr[j], dr);
        }
        {
            float* st = T + oy * TSTR + ox0;
            *reinterpret_cast<float4*>(st)     = make_float4(rr[0], rr[1], rr[2], rr[3]);
            *reinterpret_cast<float4*>(st + 4) = make_float4(rr[4], rr[5], rr[6], rr[7]);
        }
        __syncthreads();
        #pragma unroll
        for (int k = 0; k < 5; ++k)
            if (pT[k] >= 0)
                __hip_atomic_store(&Hc[pG[k]], T[pT[k]],
                                   __ATOMIC_RELAXED, __HIP_MEMORY_SCOPE_AGENT);
        float s = allreduce_bar(slots, 2u * it + 3u, dr, red, &bc, tid, bid);
        beta = s / rTr;
        rTr  = s;
    }

    // write x (lane=row -> 16B scattered stores; 3MB once, negligible)
    float* op = out + ch * H * W + gy * W + gx0;
    *reinterpret_cast<float4*>(op)     = make_float4(xr[0], xr[1], xr[2], xr[3]);
    *reinterpret_cast<float4*>(op + 4) = make_float4(xr[4], xr[5], xr[6], xr[7]);
}

// ---------------------------------------------------------------------------
extern "C" void kernel_launch(void* const* d_in, const int* in_sizes, int n_in,
                              void* d_out, int out_size, void* d_ws, size_t ws_size,
                              hipStream_t stream)
{
    (void)in_sizes; (void)n_in; (void)out_size; (void)ws_size;
    const float* img  = (const float*)d_in[0];   // [3,512,512]
    const float* kern = (const float*)d_in[1];   // [11,11]
    const float* wts  = (const float*)d_in[2];   // [2]
    const float* gk   = (const float*)d_in[3];   // [2,3,3]
    float* out = (float*)d_out;
    float* ws  = (float*)d_ws;

    slot_init<<<1, 512, 0, stream>>>((unsigned long long*)ws);
    deconv_cg<<<dim3(NBLK), dim3(NTHR), 0, stream>>>(img, kern, wts, gk, out, ws);
}

// Round 7
// 4457.935 us; speedup vs baseline: 1.1934x; 1.0567x over previous
//
#include <hip/hip_runtime.h>

// ---------------------------------------------------------------------------
// DeconvCG: 100 CG iterations solving (K^T K + sum w_i^2 G_i^T G_i) x = K^T y
// Persistent-kernel design: 192 blocks (3ch x 8x8 tiles of 64x64), 512 thr.
// R7: force EXACTLY 1 block/CU via dynamic-LDS padding (static 51200 +
//     dynamic 40960 = 92160 B > 160KiB/2). Evidence: every 51200B build
//     (2-3 blocks/CU packable) shows 4x beyond-L2 poll traffic + 26-36ms
//     outlier dispatches; the 62976B build (R4) was clean with FETCH equal
//     to the logical frame-load volume. Packed persistent blocks desync the
//     grid at every barrier.
// x, r, p in registers; p-halo (P) + conv intermediate (T) in LDS, vector
// b128 access, row-per-lane conv mapping (R6: conflicts 3.8e8 -> 2.5e8).
// Cross-block traffic: r-only 4B strips, agent-scope relaxed atomics.
// Grid barrier fused with dot allreduce: tagged slots, parity dbuf.
// ---------------------------------------------------------------------------

static constexpr int H = 512, W = 512, CCH = 3;
static constexpr int TDIM = 64;
static constexpr int RAD = 5;
static constexpr int HALO = 10;
static constexpr int PR = TDIM + 2 * HALO;        // 84
static constexpr int PSTR = 84;                   // 336B rows: 16B-aligned
static constexpr int TR = TDIM + 2 * RAD;         // 74
static constexpr int TSTR = 76;                   // 304B rows: 16B-aligned
static constexpr int NBLK = CCH * 8 * 8;          // 192
static constexpr int NTHR = 512;
static constexpr int NITER = 100;
static constexpr int FRN = 2960;                  // frame pixels (84^2-64^2)
static constexpr int SPN = 2160;                  // strip pixels (64^2-44^2)
static constexpr int DYN_PAD = 40960;             // occupancy limiter (bytes)

// ---------------- vector LDS helpers ---------------------------------------
__device__ __forceinline__ void load18(const float* __restrict__ row, float* __restrict__ v)
{
    const float4 a = *reinterpret_cast<const float4*>(row + 0);
    const float4 b = *reinterpret_cast<const float4*>(row + 4);
    const float4 c = *reinterpret_cast<const float4*>(row + 8);
    const float4 d = *reinterpret_cast<const float4*>(row + 12);
    const float2 e = *reinterpret_cast<const float2*>(row + 16);
    v[0]=a.x; v[1]=a.y; v[2]=a.z; v[3]=a.w;
    v[4]=b.x; v[5]=b.y; v[6]=b.z; v[7]=b.w;
    v[8]=c.x; v[9]=c.y; v[10]=c.z; v[11]=c.w;
    v[12]=d.x; v[13]=d.y; v[14]=d.z; v[15]=d.w;
    v[16]=e.x; v[17]=e.y;
}

// ---------------- block reduction (deterministic) --------------------------
__device__ __forceinline__ float block_reduce0(float v, float* red, int tid)
{
    __syncthreads();
    #pragma unroll
    for (int m = 32; m; m >>= 1) v += __shfl_xor(v, m, 64);
    if ((tid & 63) == 0) red[tid >> 6] = v;
    __syncthreads();
    float s = 0.f;
    if (tid == 0) {
        #pragma unroll
        for (int i = 0; i < NTHR / 64; ++i) s += red[i];
    }
    return s;          // valid on tid 0 only
}

// ---------------- fused grid-barrier + allreduce ---------------------------
__device__ __forceinline__ float allreduce_bar(unsigned long long* slots, unsigned seq,
                                               float thread_partial,
                                               float* red, float* bc, int tid, int bid)
{
    float part = block_reduce0(thread_partial, red, tid);
    asm volatile("s_waitcnt vmcnt(0)" ::: "memory");   // drain my strip stores/loads
    __syncthreads();
    unsigned long long* buf = slots + (size_t)(seq & 1u) * 256;
    if (tid == 0) {
        unsigned long long u = ((unsigned long long)seq << 32)
                             | (unsigned long long)__float_as_uint(part);
        __hip_atomic_store(&buf[bid], u, __ATOMIC_RELAXED, __HIP_MEMORY_SCOPE_AGENT);
    }
    float mine = 0.f;
    if (tid < NBLK) {
        unsigned long long v;
        for (;;) {
            v = __hip_atomic_load(&buf[tid], __ATOMIC_RELAXED, __HIP_MEMORY_SCOPE_AGENT);
            if ((unsigned)(v >> 32) == seq) break;
            __builtin_amdgcn_s_sleep(1);
        }
        mine = __uint_as_float((unsigned)v);
    }
    float s = block_reduce0(mine, red, tid);
    if (tid == 0) *bc = s;
    __syncthreads();
    return *bc;        // bitwise-identical in every block
}

// ---------------- 11x11 convs ----------------------------------------------
// row-per-lane: consecutive lanes -> consecutive LDS rows.
__device__ __forceinline__ void conv_fwd_phase(const float* __restrict__ kern,
                                               const float* __restrict__ P_,
                                               float* __restrict__ T_,
                                               int by0, int bx0, int tid)
{
    for (int seg = tid; seg < TR * 10; seg += NTHR) {
        int chunk = seg / TR;                 // 0..9
        int ry    = seg - chunk * TR;         // 0..73
        int rx0   = chunk << 3;
        int gy    = by0 - RAD + ry;
        bool rowIn = (gy >= 0 && gy < H);
        float acc[8];
        #pragma unroll
        for (int j = 0; j < 8; ++j) acc[j] = 0.f;
        for (int a = 0; a < 11; ++a) {
            float v[18];
            load18(P_ + (ry + a) * PSTR + rx0, v);
            #pragma unroll
            for (int b = 0; b < 11; ++b) {
                float kw = kern[a * 11 + b];
                #pragma unroll
                for (int j = 0; j < 8; ++j) acc[j] = fmaf(v[b + j], kw, acc[j]);
            }
        }
        #pragma unroll
        for (int j = 0; j < 8; ++j) {
            int gx = bx0 - RAD + rx0 + j;
            bool in = rowIn && gx >= 0 && gx < W;
            acc[j] = in ? acc[j] : 0.f;          // zero outside image
        }
        float* dst = T_ + ry * TSTR + rx0;
        if (rx0 < 72) {
            *reinterpret_cast<float4*>(dst)     = make_float4(acc[0], acc[1], acc[2], acc[3]);
            *reinterpret_cast<float4*>(dst + 4) = make_float4(acc[4], acc[5], acc[6], acc[7]);
        } else {                                  // rx0==72: only cols 72,73 valid
            dst[0] = acc[0];
            dst[1] = acc[1];
        }
    }
}

// vector flip conv: requires col0 32B-aligned (multiple of 8 floats)
__device__ __forceinline__ void conv11_flip_acc_v(const float* __restrict__ src, int stride,
                                                  int row0, int col0,
                                                  const float* __restrict__ kern,
                                                  float acc[8])
{
    for (int a = 0; a < 11; ++a) {
        float v[18];
        load18(src + (row0 + a) * stride + col0, v);
        #pragma unroll
        for (int b = 0; b < 11; ++b) {
            float kw = kern[(10 - a) * 11 + (10 - b)];
            #pragma unroll
            for (int j = 0; j < 8; ++j) acc[j] = fmaf(v[b + j], kw, acc[j]);
        }
    }
}

// scalar flip conv (init only: misaligned col0)
__device__ __forceinline__ void conv11_flip_acc_s(const float* __restrict__ src, int stride,
                                                  int row0, int col0,
                                                  const float* __restrict__ kern,
                                                  float acc[8])
{
    for (int a = 0; a < 11; ++a) {
        const float* row = src + (row0 + a) * stride + col0;
        float v[18];
        #pragma unroll
        for (int b = 0; b < 18; ++b) v[b] = row[b];
        #pragma unroll
        for (int b = 0; b < 11; ++b) {
            float kw = kern[(10 - a) * 11 + (10 - b)];
            #pragma unroll
            for (int j = 0; j < 8; ++j) acc[j] = fmaf(v[b + j], kw, acc[j]);
        }
    }
}

// ---------------- regularizer term -----------------------------------------
__device__ __forceinline__ void reg_acc(const float* __restrict__ P_,
                                        const float* __restrict__ CB_,
                                        const float* __restrict__ gk,
                                        float w0sq, float w1sq,
                                        int oy, int ox0, int gy, int gx0,
                                        float acc[8])
{
    bool interior = (gy >= 1 && gy < H - 1 && gx0 >= 1 && gx0 <= W - 9);
    if (interior) {
        for (int a = 0; a < 5; ++a) {
            const float* row = P_ + (oy + 8 + a) * PSTR + ox0 + 8;   // 32B-aligned
            const float4 q0 = *reinterpret_cast<const float4*>(row);
            const float4 q1 = *reinterpret_cast<const float4*>(row + 4);
            const float4 q2 = *reinterpret_cast<const float4*>(row + 8);
            float v[12] = {q0.x,q0.y,q0.z,q0.w, q1.x,q1.y,q1.z,q1.w, q2.x,q2.y,q2.z,q2.w};
            #pragma unroll
            for (int b = 0; b < 5; ++b) {
                float cb = CB_[a * 5 + b];
                #pragma unroll
                for (int j = 0; j < 8; ++j) acc[j] = fmaf(v[b + j], cb, acc[j]);
            }
        }
    } else {
        for (int j = 0; j < 8; ++j) {
            int gx = gx0 + j;
            float racc = 0.f;
            for (int dy = -1; dy <= 1; ++dy)
                for (int dx = -1; dx <= 1; ++dx) {
                    int qy = gy + dy, qx = gx + dx;
                    if (qy >= 0 && qy < H && qx >= 0 && qx < W) {
                        float u0 = 0.f, u1 = 0.f;
                        int pr0 = oy + 10 + dy - 1, pc0 = ox0 + j + 10 + dx - 1;
                        for (int sy = 0; sy < 3; ++sy)
                            for (int sx = 0; sx < 3; ++sx) {
                                float pv = P_[(pr0 + sy) * PSTR + pc0 + sx];
                                u0 = fmaf(pv, gk[sy * 3 + sx], u0);
                                u1 = fmaf(pv, gk[9 + sy * 3 + sx], u1);
                            }
                        racc += w0sq * gk[(1 - dy) * 3 + (1 - dx)] * u0
                              + w1sq * gk[9 + (1 - dy) * 3 + (1 - dx)] * u1;
                    }
                }
            acc[j] += racc;
        }
    }
}

// ---------------- slot init (fresh tags each call) -------------------------
__global__ void slot_init(unsigned long long* slots) { slots[threadIdx.x] = 0ull; }

// ---------------- main persistent kernel -----------------------------------
__global__ void __launch_bounds__(NTHR)
deconv_cg(const float* __restrict__ img, const float* __restrict__ kern,
          const float* __restrict__ wts, const float* __restrict__ gk,
          float* __restrict__ out, float* __restrict__ ws)
{
    __shared__ alignas(16) float P[PR * PSTR + 8];   // p halo region (persistent)
    __shared__ alignas(16) float T[TR * TSTR + 8];   // conv intermediate / r staging
    __shared__ float CB[25];
    __shared__ float red[NTHR / 64];
    __shared__ float bc;
    // + DYN_PAD bytes of dynamic LDS (unused): total 92160B -> 1 block/CU.

    const int tid = threadIdx.x;
    const int bid = blockIdx.x;
    const int ch  = bid / 64;
    const int tt  = bid - ch * 64;
    const int by0 = (tt >> 3) * TDIM;
    const int bx0 = (tt & 7) * TDIM;

    const float* imgc = img + ch * H * W;
    unsigned long long* slots = (unsigned long long*)ws;   // [2][256] u64
    float* Hc = ws + 1024 + (size_t)ch * H * W;            // published r

    const float w0 = wts[0], w1 = wts[1];
    const float w0sq = w0 * w0, w1sq = w1 * w1;

    if (tid < 25) {
        int ty = tid / 5 - 2, tx = tid % 5 - 2;
        float s = 0.f;
        for (int ay = 0; ay < 3; ++ay)
            for (int ax = 0; ax < 3; ++ax) {
                int by_ = ay + ty, bx_ = ax + tx;
                if (by_ >= 0 && by_ < 3 && bx_ >= 0 && bx_ < 3)
                    s += w0sq * gk[ay * 3 + ax] * gk[by_ * 3 + bx_]
                       + w1sq * gk[9 + ay * 3 + ax] * gk[9 + by_ * 3 + bx_];
            }
        CB[tid] = s;
    }

    // owned-pixel mapping, ROW-PER-LANE: lane = row, wave = col-chunk.
    const int oy  = tid & 63;
    const int ox0 = (tid >> 6) << 3;
    const int gy  = by0 + oy;
    const int gx0 = bx0 + ox0;

    // ---- precomputed frame map (iteration-invariant): 6 slots/thread ------
    // frame = P [84x84] minus owned [10,74)^2: rows 0..9 (840), rows 74..83
    // (840), rows 10..73 x cols {0..9, 74..83} (1280)
    int fP[6], fG[6];
    #pragma unroll
    for (int k = 0; k < 6; ++k) {
        int idx = tid + k * NTHR;
        fP[k] = -1; fG[k] = -1;
        if (idx < FRN) {
            int py, px;
            if (idx < 840)       { py = idx / 84;              px = idx - py * 84; }
            else if (idx < 1680) { int t = idx - 840;  py = 74 + t / 84; px = t - (t / 84) * 84; }
            else                 { int t = idx - 1680; py = 10 + t / 20;
                                   int c = t - (t / 20) * 20;  px = (c < 10) ? c : (c + 64); }
            int iy = by0 - HALO + py, ix = bx0 - HALO + px;
            if (iy >= 0 && iy < H && ix >= 0 && ix < W) {
                fP[k] = py * PSTR + px;
                fG[k] = iy * W + ix;
            }
        }
    }
    // ---- precomputed strip publish map: 5 slots/thread ---------------------
    int pT[5], pG[5];
    #pragma unroll
    for (int k = 0; k < 5; ++k) {
        int idx = tid + k * NTHR;
        pT[k] = -1; pG[k] = 0;
        if (idx < SPN) {
            int sy, sx;
            if (idx < 640)       { sy = idx >> 6;              sx = idx & 63; }
            else if (idx < 1280) { int t = idx - 640;  sy = 54 + (t >> 6); sx = t & 63; }
            else                 { int t = idx - 1280; sy = 10 + t / 20;
                                   int c = t - (t / 20) * 20;  sx = (c < 10) ? c : (c + 44); }
            pT[k] = sy * TSTR + sx;
            pG[k] = (by0 + sy) * W + bx0 + sx;
        }
    }

    float xr[8], rr[8], pr[8];

    // ================= init: r0 = K^T y - A*x0, x0 = image, p0 = r0 ========
    for (int idx = tid; idx < PR * PR; idx += NTHR) {
        int py = idx / PR, px = idx - py * PR;
        int iy = by0 - HALO + py, ix = bx0 - HALO + px;
        float v = 0.f;
        if (iy >= 0 && iy < H && ix >= 0 && ix < W) v = imgc[iy * W + ix];
        P[py * PSTR + px] = v;
    }
    __syncthreads();
    conv_fwd_phase(kern, P, T, by0, bx0, tid);
    __syncthreads();
    float rTr, beta = 0.f;
    {
        float accA[8], accB[8];
        #pragma unroll
        for (int j = 0; j < 8; ++j) { accA[j] = 0.f; accB[j] = 0.f; }
        conv11_flip_acc_v(T, TSTR, oy, ox0, kern, accA);          // K^T K x0
        conv11_flip_acc_s(P, PSTR, oy + 5, ox0 + 5, kern, accB);  // b = K^T y
        reg_acc(P, CB, gk, w0sq, w1sq, oy, ox0, gy, gx0, accA);   // + reg x0
        float dr = 0.f;
        #pragma unroll
        for (int j = 0; j < 8; ++j) {
            float r0 = accB[j] - accA[j];
            rr[j] = r0;  pr[j] = r0;
            xr[j] = P[(oy + HALO) * PSTR + ox0 + HALO + j];
            dr = fmaf(r0, r0, dr);
        }
        __syncthreads();                         // everyone done reading T
        float* st = T + oy * TSTR + ox0;
        *reinterpret_cast<float4*>(st)     = make_float4(rr[0], rr[1], rr[2], rr[3]);
        *reinterpret_cast<float4*>(st + 4) = make_float4(rr[4], rr[5], rr[6], rr[7]);
        __syncthreads();
        #pragma unroll
        for (int k = 0; k < 5; ++k)
            if (pT[k] >= 0)
                __hip_atomic_store(&Hc[pG[k]], T[pT[k]],
                                   __ATOMIC_RELAXED, __HIP_MEMORY_SCOPE_AGENT);
        rTr = allreduce_bar(slots, 1u, dr, red, &bc, tid, bid);
    }

    // ================= CG main loop ========================================
    for (int it = 0; it < NITER; ++it) {
        // phase 1: p = r + beta*p. Owned cells from regs; frame cells updated
        // in place: P[f] = fmaf(beta, P[f]_old, r_neighbor) == neighbor's pr.
        #pragma unroll
        for (int j = 0; j < 8; ++j) pr[j] = fmaf(beta, pr[j], rr[j]);
        float fv[6];
        #pragma unroll
        for (int k = 0; k < 6; ++k)
            fv[k] = (fG[k] >= 0)
                  ? __hip_atomic_load(&Hc[fG[k]], __ATOMIC_RELAXED, __HIP_MEMORY_SCOPE_AGENT)
                  : 0.f;
        #pragma unroll
        for (int k = 0; k < 6; ++k)
            if (fG[k] >= 0)
                P[fP[k]] = fmaf(beta, P[fP[k]], fv[k]);
        {
            float* ow = P + (oy + HALO) * PSTR + ox0 + HALO;   // 8B-aligned
            *reinterpret_cast<float2*>(ow)     = make_float2(pr[0], pr[1]);
            *reinterpret_cast<float2*>(ow + 2) = make_float2(pr[2], pr[3]);
            *reinterpret_cast<float2*>(ow + 4) = make_float2(pr[4], pr[5]);
            *reinterpret_cast<float2*>(ow + 6) = make_float2(pr[6], pr[7]);
        }
        __syncthreads();

        // phase 2: t = conv(p, k)
        conv_fwd_phase(kern, P, T, by0, bx0, tid);
        __syncthreads();

        // phase 3: Ap on owned tile, dot(p,Ap)
        float Ap[8];
        float dp = 0.f;
        {
            float acc[8];
            #pragma unroll
            for (int j = 0; j < 8; ++j) acc[j] = 0.f;
            conv11_flip_acc_v(T, TSTR, oy, ox0, kern, acc);
            reg_acc(P, CB, gk, w0sq, w1sq, oy, ox0, gy, gx0, acc);
            #pragma unroll
            for (int j = 0; j < 8; ++j) {
                Ap[j] = acc[j];
                dp = fmaf(pr[j], Ap[j], dp);
            }
        }
        float pAp   = allreduce_bar(slots, 2u * it + 2u, dp, red, &bc, tid, bid);
        float alpha = rTr / pAp;

        // phase 4: update x, r; stage r in T; coalesced strip publish
        float dr = 0.f;
        #pragma unroll
        for (int j = 0; j < 8; ++j) {
            xr[j] = fmaf(alpha, pr[j], xr[j]);
            rr[j] = fmaf(-alpha, Ap[j], rr[j]);
            dr = fmaf(rr[j], rr[j], dr);
        }
        {
            float* st = T + oy * TSTR + ox0;
            *reinterpret_cast<float4*>(st)     = make_float4(rr[0], rr[1], rr[2], rr[3]);
            *reinterpret_cast<float4*>(st + 4) = make_float4(rr[4], rr[5], rr[6], rr[7]);
        }
        __syncthreads();
        #pragma unroll
        for (int k = 0; k < 5; ++k)
            if (pT[k] >= 0)
                __hip_atomic_store(&Hc[pG[k]], T[pT[k]],
                                   __ATOMIC_RELAXED, __HIP_MEMORY_SCOPE_AGENT);
        float s = allreduce_bar(slots, 2u * it + 3u, dr, red, &bc, tid, bid);
        beta = s / rTr;
        rTr  = s;
    }

    // write x (lane=row -> 16B stores spread across rows; 3MB once)
    float* op = out + ch * H * W + gy * W + gx0;
    *reinterpret_cast<float4*>(op)     = make_float4(xr[0], xr[1], xr[2], xr[3]);
    *reinterpret_cast<float4*>(op + 4) = make_float4(xr[4], xr[5], xr[6], xr[7]);
}

// ---------------------------------------------------------------------------
extern "C" void kernel_launch(void* const* d_in, const int* in_sizes, int n_in,
                              void* d_out, int out_size, void* d_ws, size_t ws_size,
                              hipStream_t stream)
{
    (void)in_sizes; (void)n_in; (void)out_size; (void)ws_size;
    const float* img  = (const float*)d_in[0];   // [3,512,512]
    const float* kern = (const float*)d_in[1];   // [11,11]
    const float* wts  = (const float*)d_in[2];   // [2]
    const float* gk   = (const float*)d_in[3];   // [2,3,3]
    float* out = (float*)d_out;
    float* ws  = (float*)d_ws;

    // Allow static+dynamic LDS > 64KB; the dynamic pad only limits occupancy.
    hipFuncSetAttribute(reinterpret_cast<const void*>(deconv_cg),
                        hipFuncAttributeMaxDynamicSharedMemorySize, DYN_PAD);

    slot_init<<<1, 512, 0, stream>>>((unsigned long long*)ws);
    deconv_cg<<<dim3(NBLK), dim3(NTHR), DYN_PAD, stream>>>(img, kern, wts, gk, out, ws);
}

// Round 8
// 4207.403 us; speedup vs baseline: 1.2645x; 1.0595x over previous
//
#include <hip/hip_runtime.h>

// ---------------------------------------------------------------------------
// DeconvCG: 100 CG iterations solving (K^T K + sum w_i^2 G_i^T G_i) x = K^T y
// R8: Chronopoulos-Gear CG -> ONE grid barrier per iteration.
//   per iter: w = A r; allreduce (rTr, rTw) fused in one dual-slot barrier;
//   beta = g/g_old, alpha = g/(d - beta*g/alpha_old);
//   p = r + beta p; s = w + beta s; x += alpha p; r -= alpha s.
//   Cross-block: w strips published BEFORE the allreduce (barrier = publish
//   fence). Neighbor r/s halo maintained in LDS by the same (alpha,beta)
//   recurrences -> bitwise-identical to the neighbors' own registers.
// Uniform regularizer: 5x5 autocorr stencil everywhere (P zero-padded) minus
//   exact boundary correction for border-ring pixels only (no more 1400-FMA
//   divergent fallback -> balanced blocks).
// 192 blocks (3ch x 8x8 tiles of 64x64), 512 thr; row-per-lane conv mapping;
// vector b128 LDS access. LDS ~62.8KB (R4-class clean footprint).
// ---------------------------------------------------------------------------

static constexpr int H = 512, W = 512, CCH = 3;
static constexpr int TDIM = 64;
static constexpr int RAD = 5;
static constexpr int HALO = 10;
static constexpr int PR = TDIM + 2 * HALO;        // 84
static constexpr int PSTR = 84;                   // 336B rows, 16B-aligned
static constexpr int TR = TDIM + 2 * RAD;         // 74
static constexpr int TSTR = 76;                   // 304B rows, 16B-aligned
static constexpr int NBLK = CCH * 8 * 8;          // 192
static constexpr int NTHR = 512;
static constexpr int NITER = 100;
static constexpr int FRN = 2960;                  // frame pixels (84^2-64^2)
static constexpr int SPN = 2160;                  // strip pixels (64^2-44^2)

// ---------------- vector LDS helpers ---------------------------------------
__device__ __forceinline__ void load18(const float* __restrict__ row, float* __restrict__ v)
{
    const float4 a = *reinterpret_cast<const float4*>(row + 0);
    const float4 b = *reinterpret_cast<const float4*>(row + 4);
    const float4 c = *reinterpret_cast<const float4*>(row + 8);
    const float4 d = *reinterpret_cast<const float4*>(row + 12);
    const float2 e = *reinterpret_cast<const float2*>(row + 16);
    v[0]=a.x; v[1]=a.y; v[2]=a.z; v[3]=a.w;
    v[4]=b.x; v[5]=b.y; v[6]=b.z; v[7]=b.w;
    v[8]=c.x; v[9]=c.y; v[10]=c.z; v[11]=c.w;
    v[12]=d.x; v[13]=d.y; v[14]=d.z; v[15]=d.w;
    v[16]=e.x; v[17]=e.y;
}

// ---------------- fused grid barrier + DUAL allreduce ----------------------
// Reduces (va, vb) over all 192 blocks with one barrier. Slots: u64 tagged
// (seq<<32)|float_bits, parity double-buffered; arrays A and B posted
// consecutively. All blocks sum the 192 partials with the identical tree ->
// bitwise-identical results everywhere. The pre-post vmcnt(0)+barrier also
// fences this block's strip stores (published w visible before tag).
__device__ __forceinline__ float2 allreduce2_bar(unsigned long long* slots, unsigned seq,
                                                 float va, float vb,
                                                 float* redA, float* redB, float2* bc,
                                                 int tid, int bid)
{
    __syncthreads();                 // protect red arrays from previous use
    #pragma unroll
    for (int m = 32; m; m >>= 1) { va += __shfl_xor(va, m, 64); vb += __shfl_xor(vb, m, 64); }
    if ((tid & 63) == 0) { redA[tid >> 6] = va; redB[tid >> 6] = vb; }
    asm volatile("s_waitcnt vmcnt(0)" ::: "memory");   // drain my strip stores
    __syncthreads();                 // red ready + all waves drained
    unsigned long long* bufA = slots + (size_t)(seq & 1u) * 512;
    unsigned long long* bufB = bufA + 256;
    if (tid == 0) {
        float sa = 0.f, sb = 0.f;
        #pragma unroll
        for (int i = 0; i < NTHR / 64; ++i) { sa += redA[i]; sb += redB[i]; }
        __hip_atomic_store(&bufA[bid],
            ((unsigned long long)seq << 32) | (unsigned long long)__float_as_uint(sa),
            __ATOMIC_RELAXED, __HIP_MEMORY_SCOPE_AGENT);
        __hip_atomic_store(&bufB[bid],
            ((unsigned long long)seq << 32) | (unsigned long long)__float_as_uint(sb),
            __ATOMIC_RELAXED, __HIP_MEMORY_SCOPE_AGENT);
    }
    float ma = 0.f, mb = 0.f;
    if (tid < NBLK) {
        unsigned long long v;
        for (;;) {
            v = __hip_atomic_load(&bufA[tid], __ATOMIC_RELAXED, __HIP_MEMORY_SCOPE_AGENT);
            if ((unsigned)(v >> 32) == seq) break;
            __builtin_amdgcn_s_sleep(1);
        }
        ma = __uint_as_float((unsigned)v);
        for (;;) {
            v = __hip_atomic_load(&bufB[tid], __ATOMIC_RELAXED, __HIP_MEMORY_SCOPE_AGENT);
            if ((unsigned)(v >> 32) == seq) break;
            __builtin_amdgcn_s_sleep(1);
        }
        mb = __uint_as_float((unsigned)v);
    }
    __syncthreads();                 // red arrays reused
    #pragma unroll
    for (int m = 32; m; m >>= 1) { ma += __shfl_xor(ma, m, 64); mb += __shfl_xor(mb, m, 64); }
    if ((tid & 63) == 0) { redA[tid >> 6] = ma; redB[tid >> 6] = mb; }
    __syncthreads();
    if (tid == 0) {
        float sa = 0.f, sb = 0.f;
        #pragma unroll
        for (int i = 0; i < NTHR / 64; ++i) { sa += redA[i]; sb += redB[i]; }
        bc->x = sa; bc->y = sb;
    }
    __syncthreads();
    return *bc;
}

// ---------------- 11x11 convs (row-per-lane mapping) -----------------------
__device__ __forceinline__ void conv_fwd_phase(const float* __restrict__ kern,
                                               const float* __restrict__ P_,
                                               float* __restrict__ T_,
                                               int by0, int bx0, int tid)
{
    for (int seg = tid; seg < TR * 10; seg += NTHR) {
        int chunk = seg / TR;                 // 0..9
        int ry    = seg - chunk * TR;         // 0..73
        int rx0   = chunk << 3;
        int gy    = by0 - RAD + ry;
        bool rowIn = (gy >= 0 && gy < H);
        float acc[8];
        #pragma unroll
        for (int j = 0; j < 8; ++j) acc[j] = 0.f;
        for (int a = 0; a < 11; ++a) {
            float v[18];
            load18(P_ + (ry + a) * PSTR + rx0, v);
            #pragma unroll
            for (int b = 0; b < 11; ++b) {
                float kw = kern[a * 11 + b];
                #pragma unroll
                for (int j = 0; j < 8; ++j) acc[j] = fmaf(v[b + j], kw, acc[j]);
            }
        }
        #pragma unroll
        for (int j = 0; j < 8; ++j) {
            int gx = bx0 - RAD + rx0 + j;
            bool in = rowIn && gx >= 0 && gx < W;
            acc[j] = in ? acc[j] : 0.f;          // intermediate truncation
        }
        float* dst = T_ + ry * TSTR + rx0;
        if (rx0 < 72) {
            *reinterpret_cast<float4*>(dst)     = make_float4(acc[0], acc[1], acc[2], acc[3]);
            *reinterpret_cast<float4*>(dst + 4) = make_float4(acc[4], acc[5], acc[6], acc[7]);
        } else {
            dst[0] = acc[0];
            dst[1] = acc[1];
        }
    }
}

__device__ __forceinline__ void conv11_flip_acc_v(const float* __restrict__ src, int stride,
                                                  int row0, int col0,
                                                  const float* __restrict__ kern,
                                                  float acc[8])
{
    for (int a = 0; a < 11; ++a) {
        float v[18];
        load18(src + (row0 + a) * stride + col0, v);
        #pragma unroll
        for (int b = 0; b < 11; ++b) {
            float kw = kern[(10 - a) * 11 + (10 - b)];
            #pragma unroll
            for (int j = 0; j < 8; ++j) acc[j] = fmaf(v[b + j], kw, acc[j]);
        }
    }
}

// scalar flip conv (init only: misaligned col0)
__device__ __forceinline__ void conv11_flip_acc_s(const float* __restrict__ src, int stride,
                                                  int row0, int col0,
                                                  const float* __restrict__ kern,
                                                  float acc[8])
{
    for (int a = 0; a < 11; ++a) {
        const float* row = src + (row0 + a) * stride + col0;
        float v[18];
        #pragma unroll
        for (int b = 0; b < 18; ++b) v[b] = row[b];
        #pragma unroll
        for (int b = 0; b < 11; ++b) {
            float kw = kern[(10 - a) * 11 + (10 - b)];
            #pragma unroll
            for (int j = 0; j < 8; ++j) acc[j] = fmaf(v[b + j], kw, acc[j]);
        }
    }
}

// ---------------- uniform regularizer --------------------------------------
// Interior 5x5 autocorr stencil for ALL pixels (P zero-padded), then exact
// boundary correction: subtract terms of outside-image intermediate cells
// (only pixels on the image border ring; <=5 q's x ~20 FMA).
__device__ __forceinline__ void reg_uniform(const float* __restrict__ P_,
                                            const float* __restrict__ CB_,
                                            const float* __restrict__ gk,
                                            float w0sq, float w1sq,
                                            int oy, int ox0, int gy, int gx0,
                                            float acc[8])
{
    for (int a = 0; a < 5; ++a) {
        const float* row = P_ + (oy + 8 + a) * PSTR + ox0 + 8;   // 16B-aligned
        const float4 q0 = *reinterpret_cast<const float4*>(row);
        const float4 q1 = *reinterpret_cast<const float4*>(row + 4);
        const float4 q2 = *reinterpret_cast<const float4*>(row + 8);
        float v[12] = {q0.x,q0.y,q0.z,q0.w, q1.x,q1.y,q1.z,q1.w, q2.x,q2.y,q2.z,q2.w};
        #pragma unroll
        for (int b = 0; b < 5; ++b) {
            float cb = CB_[a * 5 + b];
            #pragma unroll
            for (int j = 0; j < 8; ++j) acc[j] = fmaf(v[b + j], cb, acc[j]);
        }
    }
    if (!(gy > 0 && gy < H - 1 && gx0 > 0 && gx0 + 7 < W - 1)) {
        for (int j = 0; j < 8; ++j) {
            int gx = gx0 + j;
            if (gy > 0 && gy < H - 1 && gx > 0 && gx < W - 1) continue;
            float corr = 0.f;
            for (int dy = -1; dy <= 1; ++dy)
                for (int dx = -1; dx <= 1; ++dx) {
                    int qy = gy + dy, qx = gx + dx;
                    if (qy >= 0 && qy < H && qx >= 0 && qx < W) continue;  // outside only
                    float u0 = 0.f, u1 = 0.f;
                    int pr0 = oy + HALO + dy - 1, pc0 = ox0 + j + HALO + dx - 1;
                    for (int sy = 0; sy < 3; ++sy)
                        for (int sx = 0; sx < 3; ++sx) {
                            float pv = P_[(pr0 + sy) * PSTR + pc0 + sx];
                            u0 = fmaf(pv, gk[sy * 3 + sx], u0);
                            u1 = fmaf(pv, gk[9 + sy * 3 + sx], u1);
                        }
                    corr += w0sq * gk[(1 - dy) * 3 + (1 - dx)] * u0
                          + w1sq * gk[9 + (1 - dy) * 3 + (1 - dx)] * u1;
                }
            acc[j] -= corr;
        }
    }
}

// ---------------- slot init (fresh tags each call) -------------------------
__global__ void slot_init(unsigned long long* slots) { slots[threadIdx.x] = 0ull; }

// ---------------- main persistent kernel -----------------------------------
__global__ void __launch_bounds__(NTHR)
deconv_cg(const float* __restrict__ img, const float* __restrict__ kern,
          const float* __restrict__ wts, const float* __restrict__ gk,
          float* __restrict__ out, float* __restrict__ ws)
{
    __shared__ alignas(16) float P[PR * PSTR + 8];   // r halo image (persistent)
    __shared__ alignas(16) float T[TR * TSTR + 8];   // conv intermediate / staging
    __shared__ float Sf[FRN];                        // frame s (=Ap) recurrence
    __shared__ float CB[25];
    __shared__ float redA[NTHR / 64], redB[NTHR / 64];
    __shared__ float2 bc2;

    const int tid = threadIdx.x;
    const int bid = blockIdx.x;
    const int ch  = bid / 64;
    const int tt  = bid - ch * 64;
    const int by0 = (tt >> 3) * TDIM;
    const int bx0 = (tt & 7) * TDIM;

    const float* imgc = img + ch * H * W;
    unsigned long long* slots = (unsigned long long*)ws;   // [2][2][256] u64 = 8KB
    float* Hc = ws + 2048 + (size_t)ch * H * W;            // published strips

    const float w0 = wts[0], w1 = wts[1];
    const float w0sq = w0 * w0, w1sq = w1 * w1;

    if (tid < 25) {
        int ty = tid / 5 - 2, tx = tid % 5 - 2;
        float s = 0.f;
        for (int ay = 0; ay < 3; ++ay)
            for (int ax = 0; ax < 3; ++ax) {
                int by_ = ay + ty, bx_ = ax + tx;
                if (by_ >= 0 && by_ < 3 && bx_ >= 0 && bx_ < 3)
                    s += w0sq * gk[ay * 3 + ax] * gk[by_ * 3 + bx_]
                       + w1sq * gk[9 + ay * 3 + ax] * gk[9 + by_ * 3 + bx_];
            }
        CB[tid] = s;
    }

    // owned-pixel mapping, row-per-lane: lane = row, wave = col-chunk.
    const int oy  = tid & 63;
    const int ox0 = (tid >> 6) << 3;
    const int gy  = by0 + oy;
    const int gx0 = bx0 + ox0;

    // ---- frame map: P [84x84] minus owned [10,74)^2 (6 slots/thread) ------
    int fP[6], fG[6], fS[6];
    #pragma unroll
    for (int k = 0; k < 6; ++k) {
        int idx = tid + k * NTHR;
        fP[k] = -1; fG[k] = -1; fS[k] = idx;
        if (idx < FRN) {
            int py, px;
            if (idx < 840)       { py = idx / 84;              px = idx - py * 84; }
            else if (idx < 1680) { int t = idx - 840;  py = 74 + t / 84; px = t - (t / 84) * 84; }
            else                 { int t = idx - 1680; py = 10 + t / 20;
                                   int c = t - (t / 20) * 20;  px = (c < 10) ? c : (c + 64); }
            int iy = by0 - HALO + py, ix = bx0 - HALO + px;
            if (iy >= 0 && iy < H && ix >= 0 && ix < W) {
                fP[k] = py * PSTR + px;
                fG[k] = iy * W + ix;
            }
        }
    }
    // ---- strip publish map (5 slots/thread) --------------------------------
    int pT[5], pG[5];
    #pragma unroll
    for (int k = 0; k < 5; ++k) {
        int idx = tid + k * NTHR;
        pT[k] = -1; pG[k] = 0;
        if (idx < SPN) {
            int sy, sx;
            if (idx < 640)       { sy = idx >> 6;              sx = idx & 63; }
            else if (idx < 1280) { int t = idx - 640;  sy = 54 + (t >> 6); sx = t & 63; }
            else                 { int t = idx - 1280; sy = 10 + t / 20;
                                   int c = t - (t / 20) * 20;  sx = (c < 10) ? c : (c + 44); }
            pT[k] = sy * TSTR + sx;
            pG[k] = (by0 + sy) * W + bx0 + sx;
        }
    }

    float xr[8], rr[8], pr[8], sr[8];
    #pragma unroll
    for (int j = 0; j < 8; ++j) { pr[j] = 0.f; sr[j] = 0.f; }
    for (int idx = tid; idx < FRN; idx += NTHR) Sf[idx] = 0.f;

    // ================= init: r0 = K^T y - A x0, x0 = image =================
    for (int idx = tid; idx < PR * PR; idx += NTHR) {
        int py = idx / PR, px = idx - py * PR;
        int iy = by0 - HALO + py, ix = bx0 - HALO + px;
        float v = 0.f;
        if (iy >= 0 && iy < H && ix >= 0 && ix < W) v = imgc[iy * W + ix];
        P[py * PSTR + px] = v;
    }
    __syncthreads();
    conv_fwd_phase(kern, P, T, by0, bx0, tid);
    __syncthreads();
    {
        float accA[8], accB[8];
        #pragma unroll
        for (int j = 0; j < 8; ++j) { accA[j] = 0.f; accB[j] = 0.f; }
        conv11_flip_acc_v(T, TSTR, oy, ox0, kern, accA);           // K^T K x0
        conv11_flip_acc_s(P, PSTR, oy + 5, ox0 + 5, kern, accB);   // b = K^T y
        reg_uniform(P, CB, gk, w0sq, w1sq, oy, ox0, gy, gx0, accA);
        #pragma unroll
        for (int j = 0; j < 8; ++j) {
            rr[j] = accB[j] - accA[j];
            xr[j] = P[(oy + HALO) * PSTR + ox0 + HALO + j];        // x0 = image
        }
        __syncthreads();                        // everyone done reading T
        float* st = T + oy * TSTR + ox0;
        *reinterpret_cast<float4*>(st)     = make_float4(rr[0], rr[1], rr[2], rr[3]);
        *reinterpret_cast<float4*>(st + 4) = make_float4(rr[4], rr[5], rr[6], rr[7]);
        __syncthreads();
        #pragma unroll
        for (int k = 0; k < 5; ++k)
            if (pT[k] >= 0)
                __hip_atomic_store(&Hc[pG[k]], T[pT[k]],
                                   __ATOMIC_RELAXED, __HIP_MEMORY_SCOPE_AGENT);
        (void)allreduce2_bar(slots, 1u, 0.f, 0.f, redA, redB, &bc2, tid, bid);
        // stage r0 into P: frame from neighbors' strips, owned from regs
        #pragma unroll
        for (int k = 0; k < 6; ++k)
            if (fG[k] >= 0)
                P[fP[k]] = __hip_atomic_load(&Hc[fG[k]],
                                             __ATOMIC_RELAXED, __HIP_MEMORY_SCOPE_AGENT);
        float* ow = P + (oy + HALO) * PSTR + ox0 + HALO;
        *reinterpret_cast<float2*>(ow)     = make_float2(rr[0], rr[1]);
        *reinterpret_cast<float2*>(ow + 2) = make_float2(rr[2], rr[3]);
        *reinterpret_cast<float2*>(ow + 4) = make_float2(rr[4], rr[5]);
        *reinterpret_cast<float2*>(ow + 6) = make_float2(rr[6], rr[7]);
    }

    float gamma_old = 1.f, alpha_old = 1.f;

    // ================= CG-CG main loop (ONE barrier/iter) ==================
    for (int it = 0; it < NITER; ++it) {
        __syncthreads();                        // P(r) writes visible

        // w = A r
        conv_fwd_phase(kern, P, T, by0, bx0, tid);
        __syncthreads();
        float wv[8];
        float ga = 0.f, de = 0.f;
        {
            float acc[8];
            #pragma unroll
            for (int j = 0; j < 8; ++j) acc[j] = 0.f;
            conv11_flip_acc_v(T, TSTR, oy, ox0, kern, acc);
            reg_uniform(P, CB, gk, w0sq, w1sq, oy, ox0, gy, gx0, acc);
            #pragma unroll
            for (int j = 0; j < 8; ++j) {
                wv[j] = acc[j];
                ga = fmaf(rr[j], rr[j], ga);
                de = fmaf(rr[j], wv[j], de);
            }
        }
        // publish w strips (before the barrier -> fenced by it)
        __syncthreads();                        // done reading T
        float* st = T + oy * TSTR + ox0;
        *reinterpret_cast<float4*>(st)     = make_float4(wv[0], wv[1], wv[2], wv[3]);
        *reinterpret_cast<float4*>(st + 4) = make_float4(wv[4], wv[5], wv[6], wv[7]);
        __syncthreads();
        #pragma unroll
        for (int k = 0; k < 5; ++k)
            if (pT[k] >= 0)
                __hip_atomic_store(&Hc[pG[k]], T[pT[k]],
                                   __ATOMIC_RELAXED, __HIP_MEMORY_SCOPE_AGENT);

        float2 gd = allreduce2_bar(slots, (unsigned)(it + 2), ga, de,
                                   redA, redB, &bc2, tid, bid);
        float gamma = gd.x, delta = gd.y;
        float beta  = (it == 0) ? 0.f : gamma / gamma_old;
        float alpha = (it == 0) ? gamma / delta
                                : gamma / (delta - beta * gamma / alpha_old);

        // neighbor w frame
        float wf[6];
        #pragma unroll
        for (int k = 0; k < 6; ++k)
            wf[k] = (fG[k] >= 0)
                  ? __hip_atomic_load(&Hc[fG[k]], __ATOMIC_RELAXED, __HIP_MEMORY_SCOPE_AGENT)
                  : 0.f;

        // register updates (owned)
        #pragma unroll
        for (int j = 0; j < 8; ++j) {
            pr[j] = fmaf(beta, pr[j], rr[j]);    // p = r + beta p
            sr[j] = fmaf(beta, sr[j], wv[j]);    // s = w + beta s
            xr[j] = fmaf(alpha, pr[j], xr[j]);   // x += alpha p
            rr[j] = fmaf(-alpha, sr[j], rr[j]);  // r -= alpha s
        }
        // frame updates (bitwise == neighbors' own sr/rr recurrences)
        #pragma unroll
        for (int k = 0; k < 6; ++k)
            if (fG[k] >= 0) {
                float s = fmaf(beta, Sf[fS[k]], wf[k]);
                Sf[fS[k]] = s;
                P[fP[k]]  = fmaf(-alpha, s, P[fP[k]]);
            }
        // owned P cells <- new r
        float* ow = P + (oy + HALO) * PSTR + ox0 + HALO;
        *reinterpret_cast<float2*>(ow)     = make_float2(rr[0], rr[1]);
        *reinterpret_cast<float2*>(ow + 2) = make_float2(rr[2], rr[3]);
        *reinterpret_cast<float2*>(ow + 4) = make_float2(rr[4], rr[5]);
        *reinterpret_cast<float2*>(ow + 6) = make_float2(rr[6], rr[7]);

        gamma_old = gamma;
        alpha_old = alpha;
    }

    // write x
    float* op = out + ch * H * W + gy * W + gx0;
    *reinterpret_cast<float4*>(op)     = make_float4(xr[0], xr[1], xr[2], xr[3]);
    *reinterpret_cast<float4*>(op + 4) = make_float4(xr[4], xr[5], xr[6], xr[7]);
}

// ---------------------------------------------------------------------------
extern "C" void kernel_launch(void* const* d_in, const int* in_sizes, int n_in,
                              void* d_out, int out_size, void* d_ws, size_t ws_size,
                              hipStream_t stream)
{
    (void)in_sizes; (void)n_in; (void)out_size; (void)ws_size;
    const float* img  = (const float*)d_in[0];   // [3,512,512]
    const float* kern = (const float*)d_in[1];   // [11,11]
    const float* wts  = (const float*)d_in[2];   // [2]
    const float* gk   = (const float*)d_in[3];   // [2,3,3]
    float* out = (float*)d_out;
    float* ws  = (float*)d_ws;

    slot_init<<<1, 1024, 0, stream>>>((unsigned long long*)ws);
    deconv_cg<<<dim3(NBLK), dim3(NTHR), 0, stream>>>(img, kern, wts, gk, out, ws);
}